// Round 1
// baseline (401.381 us; speedup 1.0000x reference)
//
#include <hip/hip_runtime.h>
#include <math.h>

#define F_CH 12
#define C_DIM 200
#define HW 225
#define PERB (C_DIM*HW)      /* 45000 */
#define PERB4 (PERB/4)       /* 11250 */
#define LN_EPS 1e-5f

/* ws layout (floats) */
#define WS_WT   0        /* 7200: wT[c][36] = {w11[:,c], w21[:,c], w31[:,c]} */
#define WS_DP   7200     /* 200:  D'[c] = d[c] - mean(d) */
#define WS_VARD 7400     /* 1:    mean(D'^2) */

__global__ __launch_bounds__(256) void k_prep(
    const float* __restrict__ w11, const float* __restrict__ w21,
    const float* __restrict__ w31, const float* __restrict__ b41,
    const float* __restrict__ w42, const float* __restrict__ b42,
    float* __restrict__ wT, float* __restrict__ Dp, float* __restrict__ varD)
{
    const int tid = threadIdx.x;
    for (int i = tid; i < 36*C_DIM; i += 256) {
        int c = i / 36, g = i - 36*c;
        float v;
        if (g < 12)      v = w11[g*C_DIM + c];
        else if (g < 24) v = w21[(g-12)*C_DIM + c];
        else             v = w31[(g-24)*C_DIM + c];
        wT[i] = v;
    }
    __shared__ float red[12];
    __shared__ float DmSh;
    float d = 0.f;
    if (tid < C_DIM) {
        float s = b42[tid];
#pragma unroll
        for (int j = 0; j < 6; ++j) s = fmaf(w42[tid*6+j], b41[j], s);
        d = s;
    }
    float s0 = d;
    for (int o = 32; o > 0; o >>= 1) s0 += __shfl_down(s0, o, 64);
    if ((tid & 63) == 0) red[tid >> 6] = s0;
    __syncthreads();
    if (tid == 0) DmSh = (red[0]+red[1]+red[2]+red[3]) * (1.f/C_DIM);
    __syncthreads();
    float dp = (tid < C_DIM) ? (d - DmSh) : 0.f;
    if (tid < C_DIM) Dp[tid] = dp;
    float s1 = dp*dp;
    for (int o = 32; o > 0; o >>= 1) s1 += __shfl_down(s1, o, 64);
    if ((tid & 63) == 0) red[4 + (tid >> 6)] = s1;
    __syncthreads();
    if (tid == 0) varD[0] = (red[4]+red[5]+red[6]+red[7]) * (1.f/C_DIM);
}

__global__ __launch_bounds__(256) void k_main(
    const float* __restrict__ X,
    const float* __restrict__ wT,
    const float* __restrict__ b11, const float* __restrict__ b21,
    const float* __restrict__ b31,
    const float* __restrict__ w41,
    const float* __restrict__ w42,
    const float* __restrict__ Dp, const float* __restrict__ varDp,
    const float* __restrict__ ln_g, const float* __restrict__ ln_b,
    float* __restrict__ out)
{
    const int b   = blockIdx.x;
    const int tid = threadIdx.x;

    __shared__ float kqsS[HW];
    __shared__ float vmb[F_CH];
    __shared__ float vsS[F_CH];
    __shared__ float t1S[6];
    __shared__ float red[12];
    __shared__ float AmSh, varASh, covSh;
    __shared__ float AgS[C_DIM], DgS[C_DIM], blS[C_DIM];
    __shared__ float PS[HW], RS[HW];

    const float varD = varDp[0];

    float accK[F_CH], accQ[F_CH], accV[F_CH];
#pragma unroll
    for (int f = 0; f < F_CH; ++f) { accK[f] = b11[f]; accQ[f] = b21[f]; accV[f] = b31[f]; }

    /* All 256 threads run the loop (keeps weight loads wave-uniform & unconditional
       so they become scalar loads); lanes >= 225 compute a duplicate of pixel 224
       and are masked out of every store/reduction below. */
    const int n = (tid < HW) ? tid : (HW-1);
    const float* xcol = X + (size_t)b*PERB + n;
    for (int c = 0; c < C_DIM; ++c) {
        float x = xcol[c*HW];
        const float* wr = wT + c*36;
#pragma unroll
        for (int f = 0; f < F_CH; ++f) {
            accK[f] = fmaf(x, wr[f],      accK[f]);
            accQ[f] = fmaf(x, wr[12+f],   accQ[f]);
            accV[f] = fmaf(x, wr[24+f],   accV[f]);
        }
    }

    if (tid < F_CH) vmb[tid] = 0.f;
    if (tid < HW) {
        float s = 0.f;
#pragma unroll
        for (int f = 0; f < F_CH; ++f) s = fmaf(accK[f], accQ[f], s);
        kqsS[tid] = s;
    }
    __syncthreads();

    /* vm bucketing: flat index m = 12*n + f goes to bucket m/225 (raw-reshape scramble) */
    if (tid < HW) {
        int m0 = 12*tid;
        int a0 = m0/225, a1 = (m0+11)/225;
        if (a0 == a1) {
            float s = 0.f;
#pragma unroll
            for (int f = 0; f < F_CH; ++f) s += accV[f];
            atomicAdd(&vmb[a0], s);
        } else {
            int split = 225*a1 - m0;
            float sa = 0.f, sb = 0.f;
#pragma unroll
            for (int f = 0; f < F_CH; ++f) { if (f < split) sa += accV[f]; else sb += accV[f]; }
            atomicAdd(&vmb[a0], sa);
            atomicAdd(&vmb[a1], sb);
        }
    }
    __syncthreads();

    if (tid == 0) {
        float v[F_CH], mx = -1e30f;
#pragma unroll
        for (int a = 0; a < F_CH; ++a) { v[a] = vmb[a]*(1.f/HW); mx = fmaxf(mx, v[a]); }
        float s = 0.f;
#pragma unroll
        for (int a = 0; a < F_CH; ++a) { v[a] = __expf(v[a]-mx); s += v[a]; }
        float inv = 1.f/s;
#pragma unroll
        for (int a = 0; a < F_CH; ++a) vsS[a] = v[a]*inv;
    }
    __syncthreads();

    if (tid < 6) {
        float s = 0.f;
#pragma unroll
        for (int l = 0; l < F_CH; ++l) s = fmaf(w41[tid*F_CH+l], vsS[l], s);
        t1S[tid] = s;
    }
    __syncthreads();

    float A = 0.f, AD = 0.f;
    if (tid < C_DIM) {
        float s = 0.f;
#pragma unroll
        for (int j = 0; j < 6; ++j) s = fmaf(w42[tid*6+j], t1S[j], s);
        A = s;
        AD = A * Dp[tid];
    }
    float r0 = A, r1 = A*A, r2 = AD;
    for (int o = 32; o > 0; o >>= 1) {
        r0 += __shfl_down(r0, o, 64);
        r1 += __shfl_down(r1, o, 64);
        r2 += __shfl_down(r2, o, 64);
    }
    if ((tid & 63) == 0) { int w = tid>>6; red[w*3]=r0; red[w*3+1]=r1; red[w*3+2]=r2; }
    __syncthreads();
    if (tid == 0) {
        float S0 = red[0]+red[3]+red[6]+red[9];
        float S1 = red[1]+red[4]+red[7]+red[10];
        float S2 = red[2]+red[5]+red[8]+red[11];
        float Am = S0*(1.f/C_DIM);
        AmSh   = Am;
        varASh = S1*(1.f/C_DIM) - Am*Am;
        covSh  = S2*(1.f/C_DIM);
    }
    __syncthreads();

    if (tid < C_DIM) {
        float Ap = A - AmSh;
        float g  = ln_g[tid];
        AgS[tid] = Ap*g;
        DgS[tid] = Dp[tid]*g;
        blS[tid] = ln_b[tid];
    }
    if (tid < HW) {
        float kq  = kqsS[tid];
        float var = fmaf(kq*kq, varASh, fmaf(2.f*kq, covSh, varD));
        float rs  = rsqrtf(var + LN_EPS);
        PS[tid] = kq*rs;
        RS[tid] = rs;
    }
    __syncthreads();

    /* pass 2: streaming gate-multiply, float4 */
    const float4* __restrict__ X4 = (const float4*)(X + (size_t)b*PERB);
    float4* __restrict__ O4 = (float4*)(out + (size_t)b*PERB);
    for (int i = tid; i < PERB4; i += 256) {
        float4 xv = X4[i];
        float xs[4] = {xv.x, xv.y, xv.z, xv.w};
        float rs4[4];
        unsigned base = (unsigned)i*4u;
#pragma unroll
        for (int e = 0; e < 4; ++e) {
            unsigned idx = base + e;
            unsigned c  = idx / HW;
            unsigned nn = idx - c*HW;
            float xn = fmaf(PS[nn], AgS[c], fmaf(RS[nn], DgS[c], blS[c]));
            float gate = (xn > 0.f) ? (1.f/(1.f+__expf(-xn))) : 0.5f;
            rs4[e] = gate * xs[e];
        }
        float4 ov; ov.x=rs4[0]; ov.y=rs4[1]; ov.z=rs4[2]; ov.w=rs4[3];
        O4[i] = ov;
    }
}

extern "C" void kernel_launch(void* const* d_in, const int* in_sizes, int n_in,
                              void* d_out, int out_size, void* d_ws, size_t ws_size,
                              hipStream_t stream) {
    const float* X   = (const float*)d_in[0];
    const float* w11 = (const float*)d_in[1];
    const float* b11 = (const float*)d_in[2];
    const float* w21 = (const float*)d_in[3];
    const float* b21 = (const float*)d_in[4];
    const float* w31 = (const float*)d_in[5];
    const float* b31 = (const float*)d_in[6];
    const float* w41 = (const float*)d_in[7];
    const float* b41 = (const float*)d_in[8];
    const float* w42 = (const float*)d_in[9];
    const float* b42 = (const float*)d_in[10];
    const float* lng = (const float*)d_in[11];
    const float* lnb = (const float*)d_in[12];
    float* out = (float*)d_out;
    float* ws  = (float*)d_ws;

    float* wT = ws + WS_WT;
    float* Dp = ws + WS_DP;
    float* vD = ws + WS_VARD;

    hipLaunchKernelGGL(k_prep, dim3(1), dim3(256), 0, stream,
                       w11, w21, w31, b41, w42, b42, wT, Dp, vD);
    hipLaunchKernelGGL(k_main, dim3(1024), dim3(256), 0, stream,
                       X, wT, b11, b21, b31, w41, w42, Dp, vD, lng, lnb, out);
}